// Round 1
// baseline (321.183 us; speedup 1.0000x reference)
//
#include <hip/hip_runtime.h>
#include <math.h>

#define D_MODEL 1024
#define HEAD_DIM 64
#define BATCH 4
#define SEQ 2048
#define NROWS (BATCH*SEQ)  // 8192

// ---------------- Projection GEMM ----------------
// out[NROWS][64] = X[NROWS][1024] @ W[1024][64]; blockIdx.y picks Wq/Wk/Wv.
#define PBM 64
#define PBK 16

__global__ __launch_bounds__(256) void qkv_proj_kernel(
    const float* __restrict__ x,
    const float* __restrict__ Wq,
    const float* __restrict__ Wk,
    const float* __restrict__ Wv,
    float* __restrict__ ws)
{
    const int t = threadIdx.x;
    const int tx = t & 15, ty = t >> 4;
    const int row0 = blockIdx.x * PBM;
    const int mat = blockIdx.y;
    const float* W = (mat == 0) ? Wq : (mat == 1) ? Wk : Wv;
    float* out = ws + (size_t)mat * NROWS * HEAD_DIM;

    // As[k][m] (transposed store), Bs[k][n]; stride 68: 4-float aligned, banks shift by 4/row
    __shared__ float As[PBK][68];
    __shared__ float Bs[PBK][68];

    float acc[4][4] = {};
    const int lm = t >> 2;          // 0..63  A-load row
    const int lk = (t & 3) * 4;     // 0,4,8,12
    const int bk = t >> 4;          // 0..15  B-load k
    const int bn = (t & 15) * 4;    // 0..60

    for (int k0 = 0; k0 < D_MODEL; k0 += PBK) {
        __syncthreads();
        float4 av = *(const float4*)(x + (size_t)(row0 + lm) * D_MODEL + k0 + lk);
        As[lk + 0][lm] = av.x;
        As[lk + 1][lm] = av.y;
        As[lk + 2][lm] = av.z;
        As[lk + 3][lm] = av.w;
        *(float4*)(&Bs[bk][bn]) = *(const float4*)(W + (size_t)(k0 + bk) * HEAD_DIM + bn);
        __syncthreads();
        #pragma unroll
        for (int kk = 0; kk < PBK; ++kk) {
            float4 a = *(const float4*)(&As[kk][ty * 4]);
            float4 b = *(const float4*)(&Bs[kk][tx * 4]);
            float ar[4] = {a.x, a.y, a.z, a.w};
            float br[4] = {b.x, b.y, b.z, b.w};
            #pragma unroll
            for (int i = 0; i < 4; ++i)
                #pragma unroll
                for (int j = 0; j < 4; ++j)
                    acc[i][j] += ar[i] * br[j];
        }
    }
    #pragma unroll
    for (int i = 0; i < 4; ++i) {
        float4 v = make_float4(acc[i][0], acc[i][1], acc[i][2], acc[i][3]);
        *(float4*)(out + (size_t)(row0 + ty * 4 + i) * HEAD_DIM + tx * 4) = v;
    }
}

// ---------------- Causal flash attention (fp32) ----------------
#define QT 32
#define KT 32

__global__ __launch_bounds__(256) void attn_kernel(
    const float* __restrict__ ws, float* __restrict__ out)
{
    const float* Q = ws;
    const float* K = ws + (size_t)NROWS * HEAD_DIM;
    const float* V = ws + (size_t)2 * NROWS * HEAD_DIM;

    const int t = threadIdx.x;
    const int b  = blockIdx.x >> 6;   // SEQ/QT = 64 q-tiles per batch
    const int qt = blockIdx.x & 63;
    const int q0 = qt * QT;

    __shared__ float Qs[QT][68];
    __shared__ float Ks[KT][68];
    __shared__ float Vs[KT][68];
    __shared__ float Ps[QT][36];

    const int lr  = t >> 3;         // 0..31 row for loads / q index
    const int ld0 = (t & 7) * 8;    // 0..56 d-chunk

    { // load Q tile once
        const float* src = Q + ((size_t)(b * SEQ + q0 + lr)) * HEAD_DIM + ld0;
        *(float4*)(&Qs[lr][ld0])     = *(const float4*)(src);
        *(float4*)(&Qs[lr][ld0 + 4]) = *(const float4*)(src + 4);
    }

    const int q  = t >> 3;          // this thread's query row (== lr)
    const int kb = (t & 7) * 4;     // 4 k-columns per thread
    const int qglob = q0 + q;

    float m = -INFINITY, l = 0.f;
    float o[8] = {};

    for (int kt = 0; kt <= qt; ++kt) {
        const int k0 = kt * KT;
        __syncthreads();  // prev iteration done with Ks/Vs/Ps
        {
            const float* ksrc = K + ((size_t)(b * SEQ + k0 + lr)) * HEAD_DIM + ld0;
            const float* vsrc = V + ((size_t)(b * SEQ + k0 + lr)) * HEAD_DIM + ld0;
            *(float4*)(&Ks[lr][ld0])     = *(const float4*)(ksrc);
            *(float4*)(&Ks[lr][ld0 + 4]) = *(const float4*)(ksrc + 4);
            *(float4*)(&Vs[lr][ld0])     = *(const float4*)(vsrc);
            *(float4*)(&Vs[lr][ld0 + 4]) = *(const float4*)(vsrc + 4);
        }
        __syncthreads();

        // ---- scores: 4 k-columns per thread ----
        float s[4] = {};
        #pragma unroll
        for (int d4 = 0; d4 < HEAD_DIM; d4 += 4) {
            float4 qv = *(const float4*)(&Qs[q][d4]);
            #pragma unroll
            for (int j = 0; j < 4; ++j) {
                float4 kv = *(const float4*)(&Ks[kb + j][d4]);
                s[j] += qv.x * kv.x + qv.y * kv.y + qv.z * kv.z + qv.w * kv.w;
            }
        }
        float sm[4];
        #pragma unroll
        for (int j = 0; j < 4; ++j) {
            int kg = k0 + kb + j;
            sm[j] = (kg <= qglob) ? s[j] * 0.125f : -INFINITY;
        }

        // ---- online softmax (8 lanes share a q-row) ----
        float pm = fmaxf(fmaxf(sm[0], sm[1]), fmaxf(sm[2], sm[3]));
        pm = fmaxf(pm, __shfl_xor(pm, 1));
        pm = fmaxf(pm, __shfl_xor(pm, 2));
        pm = fmaxf(pm, __shfl_xor(pm, 4));
        float mn = fmaxf(m, pm);              // finite: each tile has >=1 unmasked col
        float factor = expf(m - mn);          // first tile: exp(-inf)=0
        float p[4], psum = 0.f;
        #pragma unroll
        for (int j = 0; j < 4; ++j) { p[j] = expf(sm[j] - mn); psum += p[j]; }
        psum += __shfl_xor(psum, 1);
        psum += __shfl_xor(psum, 2);
        psum += __shfl_xor(psum, 4);
        l = l * factor + psum;
        m = mn;
        #pragma unroll
        for (int j = 0; j < 8; ++j) o[j] *= factor;
        #pragma unroll
        for (int j = 0; j < 4; ++j) Ps[q][kb + j] = p[j];
        __syncthreads();

        // ---- PV accumulate: 8 d-values per thread ----
        #pragma unroll
        for (int k = 0; k < KT; ++k) {
            float pv = Ps[q][k];
            float4 v0 = *(const float4*)(&Vs[k][ld0]);
            float4 v1 = *(const float4*)(&Vs[k][ld0 + 4]);
            o[0] += pv * v0.x; o[1] += pv * v0.y; o[2] += pv * v0.z; o[3] += pv * v0.w;
            o[4] += pv * v1.x; o[5] += pv * v1.y; o[6] += pv * v1.z; o[7] += pv * v1.w;
        }
    }

    float inv = 1.f / l;
    float* dst = out + ((size_t)(b * SEQ + q0 + q)) * HEAD_DIM + ld0;
    float4 r0 = make_float4(o[0] * inv, o[1] * inv, o[2] * inv, o[3] * inv);
    float4 r1 = make_float4(o[4] * inv, o[5] * inv, o[6] * inv, o[7] * inv);
    *(float4*)(dst)     = r0;
    *(float4*)(dst + 4) = r1;
}

extern "C" void kernel_launch(void* const* d_in, const int* in_sizes, int n_in,
                              void* d_out, int out_size, void* d_ws, size_t ws_size,
                              hipStream_t stream) {
    const float* x  = (const float*)d_in[0];
    const float* Wq = (const float*)d_in[1];
    const float* Wk = (const float*)d_in[2];
    const float* Wv = (const float*)d_in[3];
    // d_in[4] = mask: known-causal (tril), applied analytically in the kernel.
    float* ws  = (float*)d_ws;   // Q | K | V, each NROWS*HEAD_DIM fp32 = 6.29 MB total
    float* out = (float*)d_out;

    dim3 gproj(NROWS / PBM, 3);
    qkv_proj_kernel<<<gproj, dim3(256), 0, stream>>>(x, Wq, Wk, Wv, ws);

    dim3 gattn(BATCH * (SEQ / QT));
    attn_kernel<<<gattn, dim3(256), 0, stream>>>(ws, out);
}

// Round 2
// 115.010 us; speedup vs baseline: 2.7927x; 2.7927x over previous
//
#include <hip/hip_runtime.h>
#include <hip/hip_bf16.h>
#include <math.h>

#define D_MODEL 1024
#define HEAD_DIM 64
#define BATCH 4
#define SEQ 2048
#define NROWS (BATCH*SEQ)   // 8192
#define LSTRIDE 72          // ushort stride: 144B rows -> <=2-way LDS bank aliasing (free)

typedef __attribute__((ext_vector_type(8))) short bf16x8;
typedef __attribute__((ext_vector_type(4))) float f32x4;

__device__ __forceinline__ ushort f2bf(float f) {
    union { float f; uint u; } a; a.f = f;
    uint r = a.u + 0x7fffu + ((a.u >> 16) & 1u);   // RNE
    return (ushort)(r >> 16);
}

// ---------------------------------------------------------------------------
// Fused cast + QKV projection: out = bf16(X[8192x1024] @ W[1024x64])
// blockIdx.y = matrix (0:Q, 1:K, 2:V^T). 4 waves, 64x64 output tile, BK=64.
// ws layout (ushort units): Q16 [0, 524288) row-major [s][64]
//                           K16 [524288, 1048576) row-major [s][64]
//                           VT16 [1048576, 1572864) transposed [b][64][2048]
// ---------------------------------------------------------------------------
__global__ __launch_bounds__(256) void qkv_proj_mfma(
    const float* __restrict__ x,
    const float* __restrict__ Wq,
    const float* __restrict__ Wk,
    const float* __restrict__ Wv,
    ushort* __restrict__ ws)
{
    const int t    = threadIdx.x;
    const int lane = t & 63;
    const int wq   = t >> 6;          // wave 0..3 -> rows wq*16..+16
    const int lo   = lane & 15;
    const int g    = lane >> 4;       // 0..3
    const int row0 = blockIdx.x * 64;
    const int mat  = blockIdx.y;
    const float* W = (mat == 0) ? Wq : (mat == 1) ? Wk : Wv;

    __shared__ ushort As[64 * LSTRIDE];   // As[m][k] bf16
    __shared__ ushort Bs[64 * LSTRIDE];   // Bs[n][k] bf16 (= W^T tile)

    f32x4 acc[4];
    #pragma unroll
    for (int nf = 0; nf < 4; ++nf) acc[nf] = f32x4{0.f, 0.f, 0.f, 0.f};

    for (int k0 = 0; k0 < D_MODEL; k0 += 64) {
        __syncthreads();
        // ---- stage X tile (64 rows x 64 k), fp32 -> bf16 ----
        #pragma unroll
        for (int i = 0; i < 4; ++i) {
            int c = t + i * 256;           // float4 index 0..1023
            int row = c >> 4, f4 = c & 15;
            float4 v = *(const float4*)(x + (size_t)(row0 + row) * D_MODEL + k0 + f4 * 4);
            ushort u0 = f2bf(v.x), u1 = f2bf(v.y), u2 = f2bf(v.z), u3 = f2bf(v.w);
            uint2 pk; pk.x = (uint)u0 | ((uint)u1 << 16); pk.y = (uint)u2 | ((uint)u3 << 16);
            *(uint2*)(&As[row * LSTRIDE + f4 * 4]) = pk;
        }
        // ---- stage W tile transposed: Bs[n][kk] = W[k0+kk][n] ----
        #pragma unroll
        for (int i = 0; i < 4; ++i) {
            int c = t + i * 256;
            int kk = c >> 4, n0 = (c & 15) * 4;
            float4 v = *(const float4*)(W + (size_t)(k0 + kk) * HEAD_DIM + n0);
            Bs[(n0 + 0) * LSTRIDE + kk] = f2bf(v.x);
            Bs[(n0 + 1) * LSTRIDE + kk] = f2bf(v.y);
            Bs[(n0 + 2) * LSTRIDE + kk] = f2bf(v.z);
            Bs[(n0 + 3) * LSTRIDE + kk] = f2bf(v.w);
        }
        __syncthreads();

        // ---- MFMA: wave's 16 rows x 64 cols, K-step 64 ----
        const int rA = wq * 16 + lo;
        #pragma unroll
        for (int kd = 0; kd < 2; ++kd) {
            bf16x8 a;
            { const uint2* p = (const uint2*)(&As[rA * LSTRIDE + kd * 32 + g * 8]);
              ((uint2*)&a)[0] = p[0]; ((uint2*)&a)[1] = p[1]; }
            #pragma unroll
            for (int nf = 0; nf < 4; ++nf) {
                bf16x8 bfr;
                { const uint2* p = (const uint2*)(&Bs[(nf * 16 + lo) * LSTRIDE + kd * 32 + g * 8]);
                  ((uint2*)&bfr)[0] = p[0]; ((uint2*)&bfr)[1] = p[1]; }
                acc[nf] = __builtin_amdgcn_mfma_f32_16x16x32_bf16(a, bfr, acc[nf], 0, 0, 0);
            }
        }
    }

    // ---- epilogue: D row = (lane>>4)*4+reg, col = lane&15 ----
    const int rowb = row0 + wq * 16 + g * 4;
    if (mat < 2) {
        ushort* o = ws + (size_t)mat * NROWS * HEAD_DIM;
        #pragma unroll
        for (int nf = 0; nf < 4; ++nf)
            #pragma unroll
            for (int r = 0; r < 4; ++r)
                o[(size_t)(rowb + r) * HEAD_DIM + nf * 16 + lo] = f2bf(acc[nf][r]);
    } else {
        ushort* vt = ws + (size_t)2 * NROWS * HEAD_DIM;
        const int b = row0 >> 11;                  // 2048 rows per batch
        const int s = (row0 & 2047) + wq * 16 + g * 4;
        #pragma unroll
        for (int nf = 0; nf < 4; ++nf)
            #pragma unroll
            for (int r = 0; r < 4; ++r)
                vt[(size_t)b * HEAD_DIM * SEQ + (size_t)(nf * 16 + lo) * SEQ + s + r] = f2bf(acc[nf][r]);
    }
}

// ---------------------------------------------------------------------------
// Causal flash attention: 1 wave per 16-query tile, KT=64, MFMA 16x16x32.
// K/V read directly from L2-resident ws (no staging). P transposed via LDS.
// ---------------------------------------------------------------------------
__global__ __launch_bounds__(64) void attn_mfma(
    const ushort* __restrict__ ws, float* __restrict__ out)
{
    const ushort* Q  = ws;
    const ushort* K  = ws + (size_t)NROWS * HEAD_DIM;
    const ushort* VT = ws + (size_t)2 * NROWS * HEAD_DIM;

    const int lane = threadIdx.x;
    const int lo = lane & 15, g = lane >> 4;
    const int bid = blockIdx.x;
    const int b  = bid & 3;
    const int qi = (SEQ / 16 - 1) - (bid >> 2);    // longest q-tiles dispatch first
    const int q0 = qi * 16;

    __shared__ ushort Ps[16 * LSTRIDE];            // P tile [16 q][64 k] bf16

    // Q A-fragments (held in registers for the whole kernel)
    bf16x8 qa[2];
    {
        const ushort* qrow = Q + (size_t)(b * SEQ + q0 + lo) * HEAD_DIM;
        qa[0] = *(const bf16x8*)(qrow + g * 8);
        qa[1] = *(const bf16x8*)(qrow + 32 + g * 8);
    }

    f32x4 od[4];
    #pragma unroll
    for (int df = 0; df < 4; ++df) od[df] = f32x4{0.f, 0.f, 0.f, 0.f};
    float m[4], ls[4];
    #pragma unroll
    for (int r = 0; r < 4; ++r) { m[r] = -INFINITY; ls[r] = 0.f; }

    const int ntiles = q0 / 64 + 1;
    for (int kt = 0; kt < ntiles; ++kt) {
        const int k0 = kt * 64;

        // ---- scores S = Q K^T : A=Q-frag, B=K rows (same per-lane layout) ----
        f32x4 sc[4];
        #pragma unroll
        for (int f = 0; f < 4; ++f) sc[f] = f32x4{0.f, 0.f, 0.f, 0.f};
        #pragma unroll
        for (int kd = 0; kd < 2; ++kd) {
            #pragma unroll
            for (int f = 0; f < 4; ++f) {
                const ushort* krow = K + (size_t)(b * SEQ + k0 + f * 16 + lo) * HEAD_DIM;
                bf16x8 kb = *(const bf16x8*)(krow + kd * 32 + g * 8);
                sc[f] = __builtin_amdgcn_mfma_f32_16x16x32_bf16(qa[kd], kb, sc[f], 0, 0, 0);
            }
        }

        // ---- mask + scale; online softmax over 16-lane groups ----
        float p[4][4];            // [k-frag][q-reg]
        float mx[4];
        #pragma unroll
        for (int r = 0; r < 4; ++r) mx[r] = -INFINITY;
        #pragma unroll
        for (int f = 0; f < 4; ++f) {
            const int kg = k0 + f * 16 + lo;
            #pragma unroll
            for (int r = 0; r < 4; ++r) {
                const int qg = q0 + g * 4 + r;
                float v = (kg <= qg) ? sc[f][r] * 0.125f : -INFINITY;
                p[f][r] = v;
                mx[r] = fmaxf(mx[r], v);
            }
        }
        #pragma unroll
        for (int d = 1; d < 16; d <<= 1)
            #pragma unroll
            for (int r = 0; r < 4; ++r) mx[r] = fmaxf(mx[r], __shfl_xor(mx[r], d));

        float psum[4];
        #pragma unroll
        for (int r = 0; r < 4; ++r) {
            float mn  = fmaxf(m[r], mx[r]);        // finite after first tile (k=0 unmasked)
            float fac = __expf(m[r] - mn);         // first tile: exp(-inf)=0
            m[r] = mn;
            ls[r] *= fac;
            #pragma unroll
            for (int df = 0; df < 4; ++df) od[df][r] *= fac;
            float s = 0.f;
            #pragma unroll
            for (int f = 0; f < 4; ++f) { p[f][r] = __expf(p[f][r] - mn); s += p[f][r]; }
            psum[r] = s;
        }
        #pragma unroll
        for (int d = 1; d < 16; d <<= 1)
            #pragma unroll
            for (int r = 0; r < 4; ++r) psum[r] += __shfl_xor(psum[r], d);
        #pragma unroll
        for (int r = 0; r < 4; ++r) ls[r] += psum[r];

        // ---- transpose P through LDS into PV A-fragment layout ----
        #pragma unroll
        for (int f = 0; f < 4; ++f)
            #pragma unroll
            for (int r = 0; r < 4; ++r)
                Ps[(g * 4 + r) * LSTRIDE + f * 16 + lo] = f2bf(p[f][r]);
        __syncthreads();   // single wave: orders LDS writes before reads
        bf16x8 pa[2];
        #pragma unroll
        for (int ks = 0; ks < 2; ++ks) {
            const uint2* pp = (const uint2*)(&Ps[lo * LSTRIDE + ks * 32 + g * 8]);
            ((uint2*)&pa[ks])[0] = pp[0]; ((uint2*)&pa[ks])[1] = pp[1];
        }
        __syncthreads();   // reads done before next iteration overwrites Ps

        // ---- O += P V : B-frag = V^T rows (d-major), contiguous in k ----
        #pragma unroll
        for (int df = 0; df < 4; ++df) {
            #pragma unroll
            for (int ks = 0; ks < 2; ++ks) {
                const ushort* vrow = VT + (size_t)b * HEAD_DIM * SEQ
                                   + (size_t)(df * 16 + lo) * SEQ + k0 + ks * 32 + g * 8;
                bf16x8 vb = *(const bf16x8*)vrow;
                od[df] = __builtin_amdgcn_mfma_f32_16x16x32_bf16(pa[ks], vb, od[df], 0, 0, 0);
            }
        }
    }

    // ---- epilogue: out[q][d] = od/ls ----
    #pragma unroll
    for (int r = 0; r < 4; ++r) {
        const float inv = 1.f / ls[r];
        float* dst = out + (size_t)(b * SEQ + q0 + g * 4 + r) * HEAD_DIM;
        #pragma unroll
        for (int df = 0; df < 4; ++df)
            dst[df * 16 + lo] = od[df][r] * inv;
    }
}

extern "C" void kernel_launch(void* const* d_in, const int* in_sizes, int n_in,
                              void* d_out, int out_size, void* d_ws, size_t ws_size,
                              hipStream_t stream) {
    const float* x  = (const float*)d_in[0];
    const float* Wq = (const float*)d_in[1];
    const float* Wk = (const float*)d_in[2];
    const float* Wv = (const float*)d_in[3];
    // d_in[4] = mask: known causal tril, applied analytically.
    ushort* ws = (ushort*)d_ws;       // Q16 | K16 | VT16 = 3.1 MB bf16
    float* out = (float*)d_out;

    qkv_proj_mfma<<<dim3(NROWS / 64, 3), dim3(256), 0, stream>>>(x, Wq, Wk, Wv, ws);
    attn_mfma<<<dim3(BATCH * (SEQ / 16)), dim3(64), 0, stream>>>(ws, out);
}

// Round 3
// 83.647 us; speedup vs baseline: 3.8398x; 1.3750x over previous
//
#include <hip/hip_runtime.h>
#include <hip/hip_bf16.h>
#include <math.h>

#define D_MODEL 1024
#define HEAD_DIM 64
#define BATCH 4
#define SEQ 2048
#define NROWS (BATCH*SEQ)   // 8192
#define LSTRIDE 72          // ushort stride, 8-aligned, <=2-way bank aliasing

#define ITEMS_PER_BATCH 320 // sum over q-tiles of ceil((q0+16)/512)
#define NITEMS (BATCH*ITEMS_PER_BATCH)   // 1280

// ws layout (ushort units):
//   Q16   [0, 524288)          bf16 [8192][64]
//   K16   [524288, 1048576)    bf16 [8192][64]
//   VT16  [1048576, 1572864)   bf16 [4][64][2048]
//   WT16  [1572864, 1769472)   bf16 [3][64][1024]   (dead after proj)
//   OPART [1572864, 2883584)   bf16 [1280][16][64]  (overlaps WT16)
//   MPART f32 [1280][16], LPART f32 [1280][16] after OPART
#define K16_OFF  (NROWS*HEAD_DIM)
#define VT16_OFF (2*NROWS*HEAD_DIM)
#define WT16_OFF (3*NROWS*HEAD_DIM)

typedef __attribute__((ext_vector_type(8))) short bf16x8;
typedef __attribute__((ext_vector_type(4))) float f32x4;

__device__ __forceinline__ ushort f2bf(float f) {
    union { float f; uint u; } a; a.f = f;
    uint r = a.u + 0x7fffu + ((a.u >> 16) & 1u);   // RNE
    return (ushort)(r >> 16);
}

__device__ __forceinline__ bf16x8 pack8(float4 a, float4 b) {
    union { bf16x8 v; ushort u[8]; } r;
    r.u[0] = f2bf(a.x); r.u[1] = f2bf(a.y); r.u[2] = f2bf(a.z); r.u[3] = f2bf(a.w);
    r.u[4] = f2bf(b.x); r.u[5] = f2bf(b.y); r.u[6] = f2bf(b.z); r.u[7] = f2bf(b.w);
    return r.v;
}

// ---------------------------------------------------------------------------
// W fp32 [1024][64] -> WT16 bf16 [mat][n][k] (transposed), via LDS tile.
// ---------------------------------------------------------------------------
__global__ __launch_bounds__(256) void wconv_kernel(
    const float* __restrict__ Wq, const float* __restrict__ Wk,
    const float* __restrict__ Wv, ushort* __restrict__ wt)
{
    const int mat = blockIdx.y;
    const int k0  = blockIdx.x * 64;
    const float* W = (mat == 0) ? Wq : (mat == 1) ? Wk : Wv;
    __shared__ ushort Ls[64 * LSTRIDE];    // Ls[n][kk]
    const int t = threadIdx.x;
    #pragma unroll
    for (int i = 0; i < 4; ++i) {
        int c = t + i * 256;               // 1024 float4s
        int kk = c >> 4, n4 = (c & 15) * 4;
        float4 v = *(const float4*)(W + (size_t)(k0 + kk) * HEAD_DIM + n4);
        Ls[(n4 + 0) * LSTRIDE + kk] = f2bf(v.x);
        Ls[(n4 + 1) * LSTRIDE + kk] = f2bf(v.y);
        Ls[(n4 + 2) * LSTRIDE + kk] = f2bf(v.z);
        Ls[(n4 + 3) * LSTRIDE + kk] = f2bf(v.w);
    }
    __syncthreads();
    #pragma unroll
    for (int i = 0; i < 2; ++i) {
        int c = t + i * 256;               // 512 16B chunks
        int n = c >> 3, k8 = (c & 7) * 8;
        *(uint4*)(wt + ((size_t)mat * 64 + n) * 1024 + k0 + k8) =
            *(const uint4*)(&Ls[n * LSTRIDE + k8]);
    }
}

// ---------------------------------------------------------------------------
// Fused QKV projection, barrier-free. 1 wave = 16 rows of x, reads x ONCE.
// A-frags: global fp32 -> cvt. B-frags: L2-resident WT16. 24 MFMA / k-step.
// ---------------------------------------------------------------------------
__global__ __launch_bounds__(64) void qkv_proj_mfma(
    const float* __restrict__ x, const ushort* __restrict__ wt,
    ushort* __restrict__ q16, ushort* __restrict__ k16, ushort* __restrict__ vt16)
{
    const int lane = threadIdx.x & 63;
    const int lo = lane & 15, g = lane >> 4;
    const int r0 = blockIdx.x * 16;

    f32x4 acc[3][4];
    #pragma unroll
    for (int m = 0; m < 3; ++m)
        #pragma unroll
        for (int nf = 0; nf < 4; ++nf) acc[m][nf] = f32x4{0.f, 0.f, 0.f, 0.f};

    const float* xrow = x + (size_t)(r0 + lo) * D_MODEL;

    #pragma unroll 2
    for (int k0 = 0; k0 < D_MODEL; k0 += 64) {
        bf16x8 a[2];
        #pragma unroll
        for (int kd = 0; kd < 2; ++kd) {
            float4 v0 = *(const float4*)(xrow + k0 + kd * 32 + g * 8);
            float4 v1 = *(const float4*)(xrow + k0 + kd * 32 + g * 8 + 4);
            a[kd] = pack8(v0, v1);
        }
        #pragma unroll
        for (int kd = 0; kd < 2; ++kd) {
            bf16x8 bfr[3][4];
            #pragma unroll
            for (int m = 0; m < 3; ++m)
                #pragma unroll
                for (int nf = 0; nf < 4; ++nf)
                    bfr[m][nf] = *(const bf16x8*)(wt +
                        ((size_t)(m * 64 + nf * 16 + lo)) * 1024 + k0 + kd * 32 + g * 8);
            #pragma unroll
            for (int m = 0; m < 3; ++m)
                #pragma unroll
                for (int nf = 0; nf < 4; ++nf)
                    acc[m][nf] = __builtin_amdgcn_mfma_f32_16x16x32_bf16(
                        a[kd], bfr[m][nf], acc[m][nf], 0, 0, 0);
        }
    }

    // epilogue: D row = g*4+r, col = lo (per m89-verified layout)
    #pragma unroll
    for (int nf = 0; nf < 4; ++nf)
        #pragma unroll
        for (int r = 0; r < 4; ++r) {
            const int rg = r0 + g * 4 + r;
            q16[(size_t)rg * HEAD_DIM + nf * 16 + lo] = f2bf(acc[0][nf][r]);
            k16[(size_t)rg * HEAD_DIM + nf * 16 + lo] = f2bf(acc[1][nf][r]);
        }
    const int b = r0 >> 11;
    const int s = (r0 & 2047) + g * 4;
    #pragma unroll
    for (int nf = 0; nf < 4; ++nf)
        #pragma unroll
        for (int r = 0; r < 4; ++r)
            vt16[(size_t)b * HEAD_DIM * SEQ + (size_t)(nf * 16 + lo) * SEQ + s + r] =
                f2bf(acc[2][nf][r]);
}

// ---------------------------------------------------------------------------
// Split-K causal flash attention partials. Item = (batch, q-tile 16, k-chunk 512).
// Per batch: q-tile qi has qi/32+1 chunks; 320 items/batch, 1280 total.
// Writes unnormalized O (bf16) + m,l (f32). No block barriers (4 indep waves).
// ---------------------------------------------------------------------------
__global__ __launch_bounds__(256) void attn_partial(
    const ushort* __restrict__ ws, ushort* __restrict__ opart,
    float* __restrict__ mpart, float* __restrict__ lpart)
{
    const ushort* Q  = ws;
    const ushort* K  = ws + (size_t)K16_OFF;
    const ushort* VT = ws + (size_t)VT16_OFF;

    const int t = threadIdx.x;
    const int lane = t & 63, wid = t >> 6;
    const int lo = lane & 15, g = lane >> 4;
    const int item = (NITEMS - 1) - (blockIdx.x * 4 + wid);  // big items first
    const int b = item / ITEMS_PER_BATCH;
    const int j = item % ITEMS_PER_BATCH;
    const int gg = (j >= 192) ? 3 : (j >= 96) ? 2 : (j >= 32) ? 1 : 0;
    const int r2 = j - 16 * gg * (gg + 1);
    const int qi = 32 * gg + r2 / (gg + 1);
    const int c  = r2 % (gg + 1);
    const int q0 = qi * 16;
    const int kstart = c * 512;
    const int kend = min(kstart + 512, q0 + 16);

    __shared__ ushort Ps[4][16 * LSTRIDE];
    ushort* ps = Ps[wid];

    bf16x8 qa[2];
    {
        const ushort* qrow = Q + (size_t)(b * SEQ + q0 + lo) * HEAD_DIM;
        qa[0] = *(const bf16x8*)(qrow + g * 8);
        qa[1] = *(const bf16x8*)(qrow + 32 + g * 8);
    }

    f32x4 od[4];
    #pragma unroll
    for (int df = 0; df < 4; ++df) od[df] = f32x4{0.f, 0.f, 0.f, 0.f};
    float m[4], ls[4];
    #pragma unroll
    for (int r = 0; r < 4; ++r) { m[r] = -INFINITY; ls[r] = 0.f; }

    for (int k0 = kstart; k0 < kend; k0 += 64) {
        // ---- S = Q K^T ----
        f32x4 sc[4];
        #pragma unroll
        for (int f = 0; f < 4; ++f) sc[f] = f32x4{0.f, 0.f, 0.f, 0.f};
        #pragma unroll
        for (int kd = 0; kd < 2; ++kd) {
            #pragma unroll
            for (int f = 0; f < 4; ++f) {
                const ushort* krow = K + (size_t)(b * SEQ + k0 + f * 16 + lo) * HEAD_DIM;
                bf16x8 kb = *(const bf16x8*)(krow + kd * 32 + g * 8);
                sc[f] = __builtin_amdgcn_mfma_f32_16x16x32_bf16(qa[kd], kb, sc[f], 0, 0, 0);
            }
        }

        // ---- mask + scale + online softmax (16-lane groups) ----
        float p[4][4], mx[4];
        #pragma unroll
        for (int r = 0; r < 4; ++r) mx[r] = -INFINITY;
        #pragma unroll
        for (int f = 0; f < 4; ++f) {
            const int kg = k0 + f * 16 + lo;
            #pragma unroll
            for (int r = 0; r < 4; ++r) {
                const int qg = q0 + g * 4 + r;
                float v = (kg <= qg) ? sc[f][r] * 0.125f : -INFINITY;
                p[f][r] = v;
                mx[r] = fmaxf(mx[r], v);
            }
        }
        #pragma unroll
        for (int d = 1; d < 16; d <<= 1)
            #pragma unroll
            for (int r = 0; r < 4; ++r) mx[r] = fmaxf(mx[r], __shfl_xor(mx[r], d));

        float psum[4];
        #pragma unroll
        for (int r = 0; r < 4; ++r) {
            float mn  = fmaxf(m[r], mx[r]);
            float fac = __expf(m[r] - mn);
            m[r] = mn;
            ls[r] *= fac;
            #pragma unroll
            for (int df = 0; df < 4; ++df) od[df][r] *= fac;
            float s = 0.f;
            #pragma unroll
            for (int f = 0; f < 4; ++f) { p[f][r] = __expf(p[f][r] - mn); s += p[f][r]; }
            psum[r] = s;
        }
        #pragma unroll
        for (int d = 1; d < 16; d <<= 1)
            #pragma unroll
            for (int r = 0; r < 4; ++r) psum[r] += __shfl_xor(psum[r], d);
        #pragma unroll
        for (int r = 0; r < 4; ++r) ls[r] += psum[r];

        // ---- transpose P via per-wave LDS (same-wave DS ops are in-order) ----
        #pragma unroll
        for (int f = 0; f < 4; ++f)
            #pragma unroll
            for (int r = 0; r < 4; ++r)
                ps[(g * 4 + r) * LSTRIDE + f * 16 + lo] = f2bf(p[f][r]);
        asm volatile("s_waitcnt lgkmcnt(0)" ::: "memory");
        bf16x8 pa[2];
        #pragma unroll
        for (int ks = 0; ks < 2; ++ks) {
            const uint2* pp = (const uint2*)(&ps[lo * LSTRIDE + ks * 32 + g * 8]);
            ((uint2*)&pa[ks])[0] = pp[0]; ((uint2*)&pa[ks])[1] = pp[1];
        }
        asm volatile("" ::: "memory");   // keep reads before next iter's writes

        // ---- O += P V ----
        #pragma unroll
        for (int df = 0; df < 4; ++df)
            #pragma unroll
            for (int ks = 0; ks < 2; ++ks) {
                const ushort* vrow = VT + (size_t)b * HEAD_DIM * SEQ
                                   + (size_t)(df * 16 + lo) * SEQ + k0 + ks * 32 + g * 8;
                bf16x8 vb = *(const bf16x8*)vrow;
                od[df] = __builtin_amdgcn_mfma_f32_16x16x32_bf16(pa[ks], vb, od[df], 0, 0, 0);
            }
    }

    // ---- store partials (unnormalized) ----
    ushort* op = opart + (size_t)item * 1024;
    #pragma unroll
    for (int df = 0; df < 4; ++df)
        #pragma unroll
        for (int r = 0; r < 4; ++r)
            op[(g * 4 + r) * 64 + df * 16 + lo] = f2bf(od[df][r]);
    if (lo == 0) {
        #pragma unroll
        for (int r = 0; r < 4; ++r) {
            mpart[item * 16 + g * 4 + r] = m[r];
            lpart[item * 16 + g * 4 + r] = ls[r];
        }
    }
}

// ---------------------------------------------------------------------------
// Combine <=4 chunk-partials per q-tile: O = sum exp(m_c-M) O_c, out = O / L.
// ---------------------------------------------------------------------------
__global__ __launch_bounds__(64) void attn_combine(
    const ushort* __restrict__ opart, const float* __restrict__ mpart,
    const float* __restrict__ lpart, float* __restrict__ out)
{
    const int lane = threadIdx.x & 63;
    const int row = lane >> 2, dq = (lane & 3) * 16;
    const int b = blockIdx.x >> 7, qi = blockIdx.x & 127;
    const int gg = qi >> 5, nch = gg + 1;
    const int base = b * ITEMS_PER_BATCH + 16 * gg * (gg + 1) + (qi - 32 * gg) * nch;

    float M = -INFINITY;
    for (int c = 0; c < nch; ++c) M = fmaxf(M, mpart[(base + c) * 16 + row]);
    float L = 0.f, acc[16] = {};
    for (int c = 0; c < nch; ++c) {
        const float w = __expf(mpart[(base + c) * 16 + row] - M);
        L += lpart[(base + c) * 16 + row] * w;
        const ushort* src = opart + (size_t)(base + c) * 1024 + row * 64 + dq;
        #pragma unroll
        for (int h = 0; h < 2; ++h) {
            bf16x8 v = *(const bf16x8*)(src + h * 8);
            #pragma unroll
            for (int i = 0; i < 8; ++i) {
                union { float f; uint u; } cv; cv.u = ((uint)(ushort)v[i]) << 16;
                acc[h * 8 + i] += w * cv.f;
            }
        }
    }
    const float inv = 1.f / L;
    float* dst = out + ((size_t)(b * SEQ + qi * 16 + row)) * HEAD_DIM + dq;
    #pragma unroll
    for (int i4 = 0; i4 < 4; ++i4)
        *(float4*)(dst + i4 * 4) = make_float4(acc[i4*4] * inv, acc[i4*4+1] * inv,
                                               acc[i4*4+2] * inv, acc[i4*4+3] * inv);
}

extern "C" void kernel_launch(void* const* d_in, const int* in_sizes, int n_in,
                              void* d_out, int out_size, void* d_ws, size_t ws_size,
                              hipStream_t stream) {
    const float* x  = (const float*)d_in[0];
    const float* Wq = (const float*)d_in[1];
    const float* Wk = (const float*)d_in[2];
    const float* Wv = (const float*)d_in[3];
    // d_in[4] = mask: known causal tril, applied analytically.
    ushort* ws16 = (ushort*)d_ws;
    ushort* q16   = ws16;
    ushort* k16   = ws16 + K16_OFF;
    ushort* vt16  = ws16 + VT16_OFF;
    ushort* wt16  = ws16 + WT16_OFF;
    ushort* opart = ws16 + WT16_OFF;               // overlaps wt16 (dead after proj)
    float*  mpart = (float*)(ws16 + WT16_OFF + (size_t)NITEMS * 1024);
    float*  lpart = mpart + NITEMS * 16;
    float*  out   = (float*)d_out;

    wconv_kernel<<<dim3(16, 3), dim3(256), 0, stream>>>(Wq, Wk, Wv, wt16);
    qkv_proj_mfma<<<dim3(NROWS / 16), dim3(64), 0, stream>>>(x, wt16, q16, k16, vt16);
    attn_partial<<<dim3(NITEMS / 4), dim3(256), 0, stream>>>(ws16, opart, mpart, lpart);
    attn_combine<<<dim3(BATCH * (SEQ / 16)), dim3(64), 0, stream>>>(opart, mpart, lpart, out);
}

// Round 4
// 73.009 us; speedup vs baseline: 4.3992x; 1.1457x over previous
//
#include <hip/hip_runtime.h>
#include <hip/hip_bf16.h>
#include <math.h>

#define D_MODEL 1024
#define HEAD_DIM 64
#define BATCH 4
#define SEQ 2048
#define NROWS (BATCH*SEQ)   // 8192
#define LSTRIDE 72          // ushort stride for P-transpose buffer (<=2-way banks)

// Attention work decomposition: block = (batch, 64-query group, 256-key chunk).
// Per batch: sum over qg=0..31 of ceil((qg+1)/4) = 144 blocks. Waves = q-tiles of 16.
#define CHUNKS_PER_BATCH 144
#define NBLK_ATTN (BATCH*CHUNKS_PER_BATCH)      // 576
#define NSLOTS (NBLK_ATTN*4)                    // 2304 partial (16x64) tiles

// ws layout (ushort units):
//   Q16   [0, 524288)        bf16 [8192][64]
//   K16   [524288, 1048576)  bf16 [8192][64]
//   VT16  [1048576, 1572864) bf16 [4][64][2048]
//   WT16  [1572864, +196608) bf16 [3*64][1024]   (dead after proj)
//   OPART [1572864, +2359296) bf16 [2304][16][64] (overlaps WT16)
//   MPART/LPART f32 [2304][16] each, after OPART
#define K16_OFF  (NROWS*HEAD_DIM)
#define VT16_OFF (2*NROWS*HEAD_DIM)
#define WT16_OFF (3*NROWS*HEAD_DIM)

typedef __attribute__((ext_vector_type(8))) short bf16x8;
typedef __attribute__((ext_vector_type(4))) float f32x4;

__device__ __forceinline__ ushort f2bf(float f) {
    union { float f; uint u; } a; a.f = f;
    uint r = a.u + 0x7fffu + ((a.u >> 16) & 1u);   // RNE
    return (ushort)(r >> 16);
}

// XOR swizzle for [R][64]-ushort LDS tiles (128B rows): 16B chunk index ^ (row&7)
__device__ __forceinline__ int swz16(int row, int c16) { return c16 ^ (row & 7); }

// ---------------------------------------------------------------------------
// W fp32 [1024][64] -> WT16 bf16 [mat*64+n][1024] (transposed), via LDS tile.
// ---------------------------------------------------------------------------
__global__ __launch_bounds__(256) void wconv_kernel(
    const float* __restrict__ Wq, const float* __restrict__ Wk,
    const float* __restrict__ Wv, ushort* __restrict__ wt)
{
    const int mat = blockIdx.y;
    const int k0  = blockIdx.x * 64;
    const float* W = (mat == 0) ? Wq : (mat == 1) ? Wk : Wv;
    __shared__ ushort Ls[64 * LSTRIDE];    // Ls[n][kk]
    const int t = threadIdx.x;
    #pragma unroll
    for (int i = 0; i < 4; ++i) {
        int c = t + i * 256;               // 1024 float4s
        int kk = c >> 4, n4 = (c & 15) * 4;
        float4 v = *(const float4*)(W + (size_t)(k0 + kk) * HEAD_DIM + n4);
        Ls[(n4 + 0) * LSTRIDE + kk] = f2bf(v.x);
        Ls[(n4 + 1) * LSTRIDE + kk] = f2bf(v.y);
        Ls[(n4 + 2) * LSTRIDE + kk] = f2bf(v.z);
        Ls[(n4 + 3) * LSTRIDE + kk] = f2bf(v.w);
    }
    __syncthreads();
    #pragma unroll
    for (int i = 0; i < 2; ++i) {
        int c = t + i * 256;               // 512 16B chunks
        int n = c >> 3, k8 = (c & 7) * 8;
        *(uint4*)(wt + ((size_t)mat * 64 + n) * D_MODEL + k0 + k8) =
            *(const uint4*)(&Ls[n * LSTRIDE + k8]);
    }
}

// ---------------------------------------------------------------------------
// Fused QKV projection. Block = 32 rows, 4 waves by column groups (48 cols each
// over the 192 = 3*64 output cols). All MFMA operands from swizzled LDS;
// next k-step's global loads issued right after the barrier (reg prefetch).
// ---------------------------------------------------------------------------
__global__ __launch_bounds__(256) void qkv_proj_mfma(
    const float* __restrict__ x, const ushort* __restrict__ wt,
    ushort* __restrict__ q16, ushort* __restrict__ k16, ushort* __restrict__ vt16)
{
    const int t = threadIdx.x;
    const int lane = t & 63, w = t >> 6;
    const int lo = lane & 15, g = lane >> 4;
    const int r0 = blockIdx.x * 32;

    __shared__ ushort Xs[32 * 64];    // [row][k] bf16, swizzled 16B chunks
    __shared__ ushort Ws[192 * 64];   // [n192][k] bf16, swizzled

    float4 xr[2];
    uint4  wr[6];

    // decode staging assignments once
    const int xrow = t >> 4,      xf4 = t & 15;        // +i*256 -> row+16*i
    const int wrow = t >> 3,      wc16 = t & 7;        // +i*256 -> row+32*i

    auto load_step = [&](int k0) {
        #pragma unroll
        for (int i = 0; i < 2; ++i)
            xr[i] = *(const float4*)(x + (size_t)(r0 + xrow + i * 16) * D_MODEL + k0 + xf4 * 4);
        #pragma unroll
        for (int i = 0; i < 6; ++i)
            wr[i] = *(const uint4*)(wt + (size_t)(wrow + i * 32) * D_MODEL + k0 + wc16 * 8);
    };
    auto write_step = [&]() {
        #pragma unroll
        for (int i = 0; i < 2; ++i) {
            int row = xrow + i * 16;
            int c16 = xf4 >> 1, h = xf4 & 1;
            uint2 pk;
            pk.x = (uint)f2bf(xr[i].x) | ((uint)f2bf(xr[i].y) << 16);
            pk.y = (uint)f2bf(xr[i].z) | ((uint)f2bf(xr[i].w) << 16);
            *(uint2*)((char*)Xs + row * 128 + swz16(row, c16) * 16 + h * 8) = pk;
        }
        #pragma unroll
        for (int i = 0; i < 6; ++i) {
            int row = wrow + i * 32;
            *(uint4*)((char*)Ws + row * 128 + swz16(row, wc16) * 16) = wr[i];
        }
    };

    f32x4 acc[2][3];
    #pragma unroll
    for (int mf = 0; mf < 2; ++mf)
        #pragma unroll
        for (int nf = 0; nf < 3; ++nf) acc[mf][nf] = f32x4{0.f, 0.f, 0.f, 0.f};

    load_step(0);
    for (int ks = 0; ks < 16; ++ks) {
        write_step();
        __syncthreads();
        if (ks < 15) load_step((ks + 1) * 64);
        #pragma unroll
        for (int kd = 0; kd < 2; ++kd) {
            bf16x8 a[2], bb[3];
            #pragma unroll
            for (int mf = 0; mf < 2; ++mf) {
                int row = mf * 16 + lo;
                a[mf] = *(const bf16x8*)((const char*)Xs + row * 128 + swz16(row, kd * 4 + g) * 16);
            }
            #pragma unroll
            for (int nf = 0; nf < 3; ++nf) {
                int row = w * 48 + nf * 16 + lo;
                bb[nf] = *(const bf16x8*)((const char*)Ws + row * 128 + swz16(row, kd * 4 + g) * 16);
            }
            #pragma unroll
            for (int mf = 0; mf < 2; ++mf)
                #pragma unroll
                for (int nf = 0; nf < 3; ++nf)
                    acc[mf][nf] = __builtin_amdgcn_mfma_f32_16x16x32_bf16(
                        a[mf], bb[nf], acc[mf][nf], 0, 0, 0);
        }
        __syncthreads();
    }

    // epilogue: D row = g*4+rr, col = lo
    #pragma unroll
    for (int mf = 0; mf < 2; ++mf)
        #pragma unroll
        for (int nf = 0; nf < 3; ++nf) {
            const int n192 = w * 48 + nf * 16 + lo;
            const int mat = n192 >> 6, col = n192 & 63;
            #pragma unroll
            for (int rr = 0; rr < 4; ++rr) {
                const int rg = r0 + mf * 16 + g * 4 + rr;
                const ushort v = f2bf(acc[mf][nf][rr]);
                if (mat == 0)      q16[(size_t)rg * HEAD_DIM + col] = v;
                else if (mat == 1) k16[(size_t)rg * HEAD_DIM + col] = v;
                else {
                    const int b = rg >> 11, s = rg & 2047;
                    vt16[((size_t)b * HEAD_DIM + col) * SEQ + s] = v;
                }
            }
        }
}

// ---------------------------------------------------------------------------
// Split-K causal flash attention partials. Block = (b, qg 64-q group, c 256-key
// chunk); 4 waves = 4 q-tiles of 16 sharing staged K/V LDS tiles (<=4 k-tiles).
// ---------------------------------------------------------------------------
__global__ __launch_bounds__(256) void attn_partial(
    const ushort* __restrict__ ws, ushort* __restrict__ opart,
    float* __restrict__ mpart, float* __restrict__ lpart)
{
    const ushort* Q  = ws;
    const ushort* K  = ws + (size_t)K16_OFF;
    const ushort* VT = ws + (size_t)VT16_OFF;

    const int t = threadIdx.x;
    const int lane = t & 63, w = t >> 6;
    const int lo = lane & 15, g = lane >> 4;

    const int bid = (NBLK_ATTN - 1) - blockIdx.x;   // big chunks first
    const int b = bid / CHUNKS_PER_BATCH;
    const int j = bid % CHUNKS_PER_BATCH;
    int tb = 0;
    while (j >= 2 * (tb + 1) * (tb + 2)) ++tb;      // band: qg in [4tb, 4tb+4), tb+1 chunks each
    const int r  = j - 2 * tb * (tb + 1);
    const int qg = 4 * tb + r / (tb + 1);
    const int c  = r % (tb + 1);
    const int kstart = c * 256;
    const int kend   = min(kstart + 256, (qg + 1) * 64);
    const int ntiles = (kend - kstart) >> 6;

    const int qi = qg * 4 + w;
    const int q0 = qi * 16;
    const int qmax = q0 + 15;

    __shared__ ushort Ks[64 * 64];       // [k][d] swizzled
    __shared__ ushort Vs[64 * 64];       // [d][k] swizzled
    __shared__ ushort Ps[4][16 * LSTRIDE];
    ushort* ps = Ps[w];

    // staging assignment: 512 16B chunks per tile, 2 per thread
    const int srow = t >> 2, sc16 = (t & 3);        // +i: c16 += 4*i
    uint4 kr[2], vr[2];
    auto load_tile = [&](int k0) {
        #pragma unroll
        for (int i = 0; i < 2; ++i) {
            kr[i] = *(const uint4*)(K + (size_t)(b * SEQ + k0 + srow) * HEAD_DIM + (sc16 + 4 * i) * 8);
            vr[i] = *(const uint4*)(VT + ((size_t)b * HEAD_DIM + srow) * SEQ + k0 + (sc16 + 4 * i) * 8);
        }
    };
    auto write_tile = [&]() {
        #pragma unroll
        for (int i = 0; i < 2; ++i) {
            *(uint4*)((char*)Ks + srow * 128 + swz16(srow, sc16 + 4 * i) * 16) = kr[i];
            *(uint4*)((char*)Vs + srow * 128 + swz16(srow, sc16 + 4 * i) * 16) = vr[i];
        }
    };

    // Q fragments (scattered read, once)
    bf16x8 qa[2];
    {
        const ushort* qrow = Q + (size_t)(b * SEQ + q0 + lo) * HEAD_DIM;
        qa[0] = *(const bf16x8*)(qrow + g * 8);
        qa[1] = *(const bf16x8*)(qrow + 32 + g * 8);
    }

    f32x4 od[4];
    #pragma unroll
    for (int df = 0; df < 4; ++df) od[df] = f32x4{0.f, 0.f, 0.f, 0.f};
    float m[4], ls[4];
    #pragma unroll
    for (int rr = 0; rr < 4; ++rr) { m[rr] = -INFINITY; ls[rr] = 0.f; }

    load_tile(kstart);
    for (int kt = 0; kt < ntiles; ++kt) {
        const int k0 = kstart + kt * 64;
        write_tile();
        __syncthreads();
        if (kt + 1 < ntiles) load_tile(k0 + 64);

        if (k0 <= qmax) {
            // ---- S = Q K^T from LDS ----
            f32x4 sc[4];
            #pragma unroll
            for (int f = 0; f < 4; ++f) sc[f] = f32x4{0.f, 0.f, 0.f, 0.f};
            #pragma unroll
            for (int kd = 0; kd < 2; ++kd)
                #pragma unroll
                for (int f = 0; f < 4; ++f) {
                    int row = f * 16 + lo;
                    bf16x8 kb = *(const bf16x8*)((const char*)Ks + row * 128 + swz16(row, kd * 4 + g) * 16);
                    sc[f] = __builtin_amdgcn_mfma_f32_16x16x32_bf16(qa[kd], kb, sc[f], 0, 0, 0);
                }

            // ---- mask + scale + online softmax (16-lane groups) ----
            float p[4][4], mx[4];
            #pragma unroll
            for (int rr = 0; rr < 4; ++rr) mx[rr] = -INFINITY;
            #pragma unroll
            for (int f = 0; f < 4; ++f) {
                const int kg = k0 + f * 16 + lo;
                #pragma unroll
                for (int rr = 0; rr < 4; ++rr) {
                    const int qrow = q0 + g * 4 + rr;
                    float v = (kg <= qrow) ? sc[f][rr] * 0.125f : -INFINITY;
                    p[f][rr] = v;
                    mx[rr] = fmaxf(mx[rr], v);
                }
            }
            #pragma unroll
            for (int d = 1; d < 16; d <<= 1)
                #pragma unroll
                for (int rr = 0; rr < 4; ++rr) mx[rr] = fmaxf(mx[rr], __shfl_xor(mx[rr], d));

            float psum[4];
            #pragma unroll
            for (int rr = 0; rr < 4; ++rr) {
                float mn  = fmaxf(m[rr], mx[rr]);
                float fac = __expf(m[rr] - mn);
                m[rr] = mn;
                ls[rr] *= fac;
                #pragma unroll
                for (int df = 0; df < 4; ++df) od[df][rr] *= fac;
                float s = 0.f;
                #pragma unroll
                for (int f = 0; f < 4; ++f) { p[f][rr] = __expf(p[f][rr] - mn); s += p[f][rr]; }
                psum[rr] = s;
            }
            #pragma unroll
            for (int d = 1; d < 16; d <<= 1)
                #pragma unroll
                for (int rr = 0; rr < 4; ++rr) psum[rr] += __shfl_xor(psum[rr], d);
            #pragma unroll
            for (int rr = 0; rr < 4; ++rr) ls[rr] += psum[rr];

            // ---- transpose P via per-wave LDS ----
            #pragma unroll
            for (int f = 0; f < 4; ++f)
                #pragma unroll
                for (int rr = 0; rr < 4; ++rr)
                    ps[(g * 4 + rr) * LSTRIDE + f * 16 + lo] = f2bf(p[f][rr]);
            asm volatile("s_waitcnt lgkmcnt(0)" ::: "memory");
            bf16x8 pa[2];
            #pragma unroll
            for (int k2 = 0; k2 < 2; ++k2) {
                const uint2* pp = (const uint2*)(&ps[lo * LSTRIDE + k2 * 32 + g * 8]);
                ((uint2*)&pa[k2])[0] = pp[0]; ((uint2*)&pa[k2])[1] = pp[1];
            }
            asm volatile("" ::: "memory");

            // ---- O += P V from LDS ----
            #pragma unroll
            for (int df = 0; df < 4; ++df)
                #pragma unroll
                for (int k2 = 0; k2 < 2; ++k2) {
                    int row = df * 16 + lo;
                    bf16x8 vb = *(const bf16x8*)((const char*)Vs + row * 128 + swz16(row, k2 * 4 + g) * 16);
                    od[df] = __builtin_amdgcn_mfma_f32_16x16x32_bf16(pa[k2], vb, od[df], 0, 0, 0);
                }
        }
        __syncthreads();
    }

    // ---- store partials (only if this wave had work; combine reads exactly these) ----
    if (kstart <= q0) {
        const int slot = bid * 4 + w;
        ushort* op = opart + (size_t)slot * 1024;
        #pragma unroll
        for (int df = 0; df < 4; ++df)
            #pragma unroll
            for (int rr = 0; rr < 4; ++rr)
                op[(g * 4 + rr) * 64 + df * 16 + lo] = f2bf(od[df][rr]);
        if (lo == 0) {
            #pragma unroll
            for (int rr = 0; rr < 4; ++rr) {
                mpart[slot * 16 + g * 4 + rr] = m[rr];
                lpart[slot * 16 + g * 4 + rr] = ls[rr];
            }
        }
    }
}

// ---------------------------------------------------------------------------
// Combine <=8 chunk-partials per 16-q tile: O = sum exp(m_c-M) O_c; out = O/L.
// ---------------------------------------------------------------------------
__global__ __launch_bounds__(64) void attn_combine(
    const ushort* __restrict__ opart, const float* __restrict__ mpart,
    const float* __restrict__ lpart, float* __restrict__ out)
{
    const int lane = threadIdx.x & 63;
    const int row = lane >> 2, dq = (lane & 3) * 16;
    const int b = blockIdx.x >> 7, qi = blockIdx.x & 127;
    const int qg = qi >> 2, w = qi & 3, tb = qg >> 2;
    const int base = b * CHUNKS_PER_BATCH + 2 * tb * (tb + 1) + (qg & 3) * (tb + 1);
    const int nch = qi / 16 + 1;    // chunks with kstart <= q0

    float M = -INFINITY;
    for (int c = 0; c < nch; ++c) M = fmaxf(M, mpart[(base + c) * 4 * 16 + w * 16 + row]);
    float L = 0.f, acc[16] = {};
    for (int c = 0; c < nch; ++c) {
        const int slot = (base + c) * 4 + w;
        const float wgt = __expf(mpart[slot * 16 + row] - M);
        L += lpart[slot * 16 + row] * wgt;
        const ushort* src = opart + (size_t)slot * 1024 + row * 64 + dq;
        #pragma unroll
        for (int h = 0; h < 2; ++h) {
            bf16x8 v = *(const bf16x8*)(src + h * 8);
            #pragma unroll
            for (int i = 0; i < 8; ++i) {
                union { float f; uint u; } cv; cv.u = ((uint)(ushort)v[i]) << 16;
                acc[h * 8 + i] += wgt * cv.f;
            }
        }
    }
    const float inv = 1.f / L;
    float* dst = out + ((size_t)(b * SEQ + qi * 16 + row)) * HEAD_DIM + dq;
    #pragma unroll
    for (int i4 = 0; i4 < 4; ++i4)
        *(float4*)(dst + i4 * 4) = make_float4(acc[i4*4] * inv, acc[i4*4+1] * inv,
                                               acc[i4*4+2] * inv, acc[i4*4+3] * inv);
}

extern "C" void kernel_launch(void* const* d_in, const int* in_sizes, int n_in,
                              void* d_out, int out_size, void* d_ws, size_t ws_size,
                              hipStream_t stream) {
    const float* x  = (const float*)d_in[0];
    const float* Wq = (const float*)d_in[1];
    const float* Wk = (const float*)d_in[2];
    const float* Wv = (const float*)d_in[3];
    // d_in[4] = mask: known causal tril, applied analytically.
    ushort* ws16 = (ushort*)d_ws;
    ushort* q16   = ws16;
    ushort* k16   = ws16 + K16_OFF;
    ushort* vt16  = ws16 + VT16_OFF;
    ushort* wt16  = ws16 + WT16_OFF;
    ushort* opart = ws16 + WT16_OFF;               // overlaps wt16 (dead after proj)
    float*  mpart = (float*)(ws16 + WT16_OFF + (size_t)NSLOTS * 1024);
    float*  lpart = mpart + NSLOTS * 16;
    float*  out   = (float*)d_out;

    wconv_kernel<<<dim3(16, 3), dim3(256), 0, stream>>>(Wq, Wk, Wv, wt16);
    qkv_proj_mfma<<<dim3(NROWS / 32), dim3(256), 0, stream>>>(x, wt16, q16, k16, vt16);
    attn_partial<<<dim3(NBLK_ATTN), dim3(256), 0, stream>>>(ws16, opart, mpart, lpart);
    attn_combine<<<dim3(BATCH * (SEQ / 16)), dim3(64), 0, stream>>>(opart, mpart, lpart, out);
}